// Round 3
// baseline (103.499 us; speedup 1.0000x reference)
//
#include <hip/hip_runtime.h>
#include <math.h>

#define MM 32
#define NN 8192
#define DD 64
#define KK 16

typedef float f32x4 __attribute__((ext_vector_type(4)));

// ---------------------------------------------------------------------------
// Kernel 1: per-component precompute via Woodbury.
//   Mk = I + Lambda^T P^{-1} Lambda  (16x16), P = diag(Psi + 1e-6)
//   Minv[m] = Mk^{-1} (== term1);  const[m] = log pi - 0.5*(D log2pi + logdet)
// ---------------------------------------------------------------------------
__global__ __launch_bounds__(256) void mfa_pre(
    const float* __restrict__ pi, const float* __restrict__ Lambda,
    const float* __restrict__ Psi, float* __restrict__ Minv_out,
    float* __restrict__ const_out) {
  const int m = blockIdx.x;
  const int tid = threadIdx.x;
  __shared__ float lam[DD * KK];
  __shared__ float pinv[DD];
  __shared__ float Mmat[KK * KK];
  __shared__ float Lmat[KK * KK];
  __shared__ float vbuf[KK];

  for (int idx = tid; idx < DD * KK; idx += 256)
    lam[idx] = Lambda[(size_t)m * DD * KK + idx];
  if (tid < DD) pinv[tid] = 1.0f / (Psi[tid] + 1e-6f);
  __syncthreads();

  {
    const int k = tid >> 4, j = tid & 15;
    float a = 0.0f;
    for (int d = 0; d < DD; ++d)
      a += lam[d * KK + k] * lam[d * KK + j] * pinv[d];
    Mmat[tid] = a + (k == j ? 1.0f : 0.0f);
  }
  __syncthreads();

  // Cooperative right-looking Cholesky: thread r owns row r in registers.
  float lr[KK];
  if (tid < KK) {
#pragma unroll
    for (int j = 0; j < KK; ++j) lr[j] = Mmat[tid * KK + j];
  }
#pragma unroll
  for (int c = 0; c < KK; ++c) {
    if (tid < KK) vbuf[tid] = lr[c];
    __syncthreads();
    if (tid < KK) {
      const float vc = vbuf[c];
      const float dc = sqrtf(vc);
      const float lrc = lr[c] / dc;
      if (tid >= c) Lmat[tid * KK + c] = lrc;
      const float s = lr[c] / vc;
#pragma unroll
      for (int j = 0; j < KK; ++j)
        if (j > c) lr[j] -= s * vbuf[j];
    }
    __syncthreads();
  }

  if (tid < KK) {
    const int col = tid;
    float y[KK], z[KK];
#pragma unroll
    for (int i = 0; i < KK; ++i) {
      float s = (i == col) ? 1.0f : 0.0f;
#pragma unroll
      for (int p = 0; p < KK; ++p)
        if (p < i) s -= Lmat[i * KK + p] * y[p];
      y[i] = s / Lmat[i * KK + i];
    }
#pragma unroll
    for (int i = KK - 1; i >= 0; --i) {
      float s = y[i];
#pragma unroll
      for (int p = 0; p < KK; ++p)
        if (p > i) s -= Lmat[p * KK + i] * z[p];
      z[i] = s / Lmat[i * KK + i];
    }
#pragma unroll
    for (int i = 0; i < KK; ++i)
      Minv_out[(size_t)m * KK * KK + i * KK + col] = z[i];
  }

  if (tid == 0) {
    float logdetM = 0.0f;
#pragma unroll
    for (int c = 0; c < KK; ++c) logdetM += logf(Lmat[c * KK + c]);
    logdetM *= 2.0f;
    float logdetP = 0.0f;
    for (int d = 0; d < DD; ++d) logdetP -= logf(pinv[d]);
    const float LOG2PI = 1.8378770664093453f;
    const_out[m] =
        logf(pi[m] + 1e-10f) - 0.5f * (DD * LOG2PI + logdetP + logdetM);
  }
}

// ---------------------------------------------------------------------------
// Kernel 2: compute pass — logits + e_z only. grid = (N/256, M), 256 threads.
// ---------------------------------------------------------------------------
__global__ __launch_bounds__(256) void mfa_compute(
    const float* __restrict__ X, const float* __restrict__ mu,
    const float* __restrict__ Lambda, const float* __restrict__ Psi,
    const float* __restrict__ Minv, const float* __restrict__ cconst,
    float* __restrict__ out) {
  const int m = blockIdx.y;
  const int n0 = blockIdx.x * 256;
  const int tid = threadIdx.x;

  __shared__ float Wl[DD * KK];      // P^{-1} Lambda_m  (4KB)
  __shared__ float pinv[DD];
  __shared__ float mul[DD];
  __shared__ float minv_l[KK * KK];  // 1KB
  __shared__ float ez_l[256 * KK];   // 16KB

  if (tid < DD) {
    pinv[tid] = 1.0f / (Psi[tid] + 1e-6f);
    mul[tid] = mu[m * DD + tid];
  }
  minv_l[tid] = Minv[(size_t)m * KK * KK + tid];
  __syncthreads();
  for (int idx = tid; idx < DD * KK; idx += 256)
    Wl[idx] = Lambda[(size_t)m * DD * KK + idx] * pinv[idx >> 4];
  __syncthreads();

  const int n = n0 + tid;
  const float cst = cconst[m];

  float u[KK];
#pragma unroll
  for (int k = 0; k < KK; ++k) u[k] = 0.0f;
  float q = 0.0f;
  const float4* X4 = reinterpret_cast<const float4*>(X + (size_t)n * DD);
#pragma unroll
  for (int d4 = 0; d4 < DD / 4; ++d4) {
    const float4 xv = X4[d4];
    const float xs[4] = {xv.x, xv.y, xv.z, xv.w};
#pragma unroll
    for (int s = 0; s < 4; ++s) {
      const int d = d4 * 4 + s;
      const float df = xs[s] - mul[d];
      q += df * df * pinv[d];
#pragma unroll
      for (int k = 0; k < KK; ++k) u[k] += Wl[d * KK + k] * df;
    }
  }

  float ez[KK];
  float udot = 0.0f;
#pragma unroll
  for (int i = 0; i < KK; ++i) {
    float s = 0.0f;
#pragma unroll
    for (int j = 0; j < KK; ++j) s += minv_l[i * KK + j] * u[j];
    ez[i] = s;
    udot += u[i] * s;
  }
  const float maha = q - udot;
  out[(size_t)n * MM + m] = cst - 0.5f * maha;  // logit; softmax later

#pragma unroll
  for (int k = 0; k < KK; ++k) ez_l[tid * KK + k] = ez[k];
  __syncthreads();

  // coalesced e_z write: 256 samples * 16 floats = 1024 float4 contiguous
  const float4* ezl4 = reinterpret_cast<const float4*>(ez_l);
  float4* ezout4 = reinterpret_cast<float4*>(
      out + (size_t)NN * MM + ((size_t)m * NN + n0) * KK);
#pragma unroll
  for (int it = 0; it < 4; ++it) ezout4[it * 256 + tid] = ezl4[it * 256 + tid];
}

// ---------------------------------------------------------------------------
// Kernel 3: pure streaming e_zz writer. Each wave writes one sample's full
// 16x16 tile (1KB, 64 lanes x float4) per iteration — perfectly coalesced
// nontemporal stores. Reads: the sample's 64B e_z row (L2/L3-hot) + per-lane
// Minv float4 held in a register. No LDS, no barriers.
//   lane l: i = l>>2, j-quad = l&3.  block covers 128 consecutive samples.
// ---------------------------------------------------------------------------
__global__ __launch_bounds__(256) void mfa_ezz(
    const float* __restrict__ ez, const float* __restrict__ Minv,
    float* __restrict__ outzz) {
  const int tid = threadIdx.x;
  const int w = tid >> 6, l = tid & 63;
  const int i_ = l >> 2, jq = l & 3;
  const long long s0 = (long long)blockIdx.x * 128;
  const int m = (int)(s0 / NN);
  const f32x4 mreg = reinterpret_cast<const f32x4*>(Minv)[m * 64 + l];
  const f32x4* ez4 = reinterpret_cast<const f32x4*>(ez);
  f32x4* out4 = reinterpret_cast<f32x4*>(outzz);
#pragma unroll 4
  for (int it = 0; it < 32; ++it) {
    const long long s = s0 + it * 4 + w;  // sample handled by this wave
    const float ezi = ez[s * KK + i_];
    const f32x4 ezj = ez4[s * 4 + jq];
    const f32x4 o = mreg + ezi * ezj;
    __builtin_nontemporal_store(o, &out4[s * 64 + l]);
  }
}

// ---------------------------------------------------------------------------
// Kernel 4: in-place softmax over the M=32 logits per sample.
// ---------------------------------------------------------------------------
__global__ __launch_bounds__(256) void mfa_softmax(float* __restrict__ out) {
  const int n = blockIdx.x * 256 + threadIdx.x;
  float4* p = reinterpret_cast<float4*>(out) + (size_t)n * (MM / 4);
  float v[MM];
#pragma unroll
  for (int i = 0; i < MM / 4; ++i) {
    const float4 t = p[i];
    v[4 * i] = t.x; v[4 * i + 1] = t.y; v[4 * i + 2] = t.z; v[4 * i + 3] = t.w;
  }
  float mx = -3.4e38f;
#pragma unroll
  for (int i = 0; i < MM; ++i) mx = fmaxf(mx, v[i]);
  float s = 0.0f;
#pragma unroll
  for (int i = 0; i < MM; ++i) { v[i] = expf(v[i] - mx); s += v[i]; }
  const float inv = 1.0f / s;
#pragma unroll
  for (int i = 0; i < MM / 4; ++i) {
    float4 t;
    t.x = v[4 * i] * inv; t.y = v[4 * i + 1] * inv;
    t.z = v[4 * i + 2] * inv; t.w = v[4 * i + 3] * inv;
    p[i] = t;
  }
}

extern "C" void kernel_launch(void* const* d_in, const int* in_sizes, int n_in,
                              void* d_out, int out_size, void* d_ws,
                              size_t ws_size, hipStream_t stream) {
  const float* X = (const float*)d_in[0];
  const float* pi = (const float*)d_in[1];
  const float* mu = (const float*)d_in[2];
  const float* Lambda = (const float*)d_in[3];
  const float* Psi = (const float*)d_in[4];
  float* out = (float*)d_out;

  float* Minv = (float*)d_ws;           // 32*256 floats = 32KB
  float* cconst = Minv + MM * KK * KK;  // 32 floats

  float* ez_out = out + (size_t)NN * MM;           // [M,N,K]
  float* ezz_out = ez_out + (size_t)MM * NN * KK;  // [M,N,K,K]

  mfa_pre<<<MM, 256, 0, stream>>>(pi, Lambda, Psi, Minv, cconst);
  mfa_compute<<<dim3(NN / 256, MM), 256, 0, stream>>>(X, mu, Lambda, Psi, Minv,
                                                      cconst, out);
  mfa_ezz<<<(MM * NN) / 128, 256, 0, stream>>>(ez_out, Minv, ezz_out);
  mfa_softmax<<<NN / 256, 256, 0, stream>>>(out);
}

// Round 4
// 79.496 us; speedup vs baseline: 1.3019x; 1.3019x over previous
//
#include <hip/hip_runtime.h>
#include <math.h>

#define MM 32
#define NN 8192
#define DD 64
#define KK 16

// ---------------------------------------------------------------------------
// Kernel 1: per-component precompute via Woodbury.
//   Mk = I + Lambda^T P^{-1} Lambda  (16x16), P = diag(Psi + 1e-6)
//   Minv[m] = Mk^{-1} (== term1);  const[m] = log pi - 0.5*(D log2pi + logdet)
// ---------------------------------------------------------------------------
__global__ __launch_bounds__(256) void mfa_pre(
    const float* __restrict__ pi, const float* __restrict__ Lambda,
    const float* __restrict__ Psi, float* __restrict__ Minv_out,
    float* __restrict__ const_out) {
  const int m = blockIdx.x;
  const int tid = threadIdx.x;
  __shared__ float lam[DD * KK];
  __shared__ float pinv[DD];
  __shared__ float Mmat[KK * KK];
  __shared__ float Lmat[KK * KK];
  __shared__ float vbuf[KK];

  for (int idx = tid; idx < DD * KK; idx += 256)
    lam[idx] = Lambda[(size_t)m * DD * KK + idx];
  if (tid < DD) pinv[tid] = 1.0f / (Psi[tid] + 1e-6f);
  __syncthreads();

  {
    const int k = tid >> 4, j = tid & 15;
    float a = 0.0f;
    for (int d = 0; d < DD; ++d)
      a += lam[d * KK + k] * lam[d * KK + j] * pinv[d];
    Mmat[tid] = a + (k == j ? 1.0f : 0.0f);
  }
  __syncthreads();

  // Cooperative right-looking Cholesky: thread r owns row r in registers.
  float lr[KK];
  if (tid < KK) {
#pragma unroll
    for (int j = 0; j < KK; ++j) lr[j] = Mmat[tid * KK + j];
  }
#pragma unroll
  for (int c = 0; c < KK; ++c) {
    if (tid < KK) vbuf[tid] = lr[c];
    __syncthreads();
    if (tid < KK) {
      const float vc = vbuf[c];
      const float dc = sqrtf(vc);
      const float lrc = lr[c] / dc;
      if (tid >= c) Lmat[tid * KK + c] = lrc;
      const float s = lr[c] / vc;
#pragma unroll
      for (int j = 0; j < KK; ++j)
        if (j > c) lr[j] -= s * vbuf[j];
    }
    __syncthreads();
  }

  if (tid < KK) {
    const int col = tid;
    float y[KK], z[KK];
#pragma unroll
    for (int i = 0; i < KK; ++i) {
      float s = (i == col) ? 1.0f : 0.0f;
#pragma unroll
      for (int p = 0; p < KK; ++p)
        if (p < i) s -= Lmat[i * KK + p] * y[p];
      y[i] = s / Lmat[i * KK + i];
    }
#pragma unroll
    for (int i = KK - 1; i >= 0; --i) {
      float s = y[i];
#pragma unroll
      for (int p = 0; p < KK; ++p)
        if (p > i) s -= Lmat[p * KK + i] * z[p];
      z[i] = s / Lmat[i * KK + i];
    }
#pragma unroll
    for (int i = 0; i < KK; ++i)
      Minv_out[(size_t)m * KK * KK + i * KK + col] = z[i];
  }

  if (tid == 0) {
    float logdetM = 0.0f;
#pragma unroll
    for (int c = 0; c < KK; ++c) logdetM += logf(Lmat[c * KK + c]);
    logdetM *= 2.0f;
    float logdetP = 0.0f;
    for (int d = 0; d < DD; ++d) logdetP -= logf(pinv[d]);
    const float LOG2PI = 1.8378770664093453f;
    const_out[m] =
        logf(pi[m] + 1e-10f) - 0.5f * (DD * LOG2PI + logdetP + logdetM);
  }
}

// ---------------------------------------------------------------------------
// Kernel 2: fused main pass, WAVE-LOCAL pipeline. grid = (N/256, M).
// Each wave owns 64 consecutive samples end-to-end: compute u/e_z/logit,
// stage e_z in its private 4KB LDS slice, then stream its 4KB e_z + 64KB
// e_zz without any block-wide barrier. Waves de-phase naturally, so some
// waves compute while others stream -> stores flow continuously.
// Wave-internal ordering: DS ops are in-order per wave; wave_barrier +
// s_waitcnt lgkmcnt(0) stops compiler reordering across the phase switch.
// ---------------------------------------------------------------------------
__global__ __launch_bounds__(256) void mfa_main(
    const float* __restrict__ X, const float* __restrict__ mu,
    const float* __restrict__ Lambda, const float* __restrict__ Psi,
    const float* __restrict__ Minv, const float* __restrict__ cconst,
    float* __restrict__ out) {
  const int m = blockIdx.y;
  const int n0 = blockIdx.x * 256;
  const int tid = threadIdx.x;
  const int w = tid >> 6, l = tid & 63;

  __shared__ float Wl[DD * KK];      // P^{-1} Lambda_m  (4KB)
  __shared__ float pinv[DD];
  __shared__ float mul[DD];
  __shared__ float minv_l[KK * KK];  // 1KB
  __shared__ float ez_l[256 * KK];   // 16KB, wave w owns [w*64*KK, +4KB)

  if (tid < DD) {
    pinv[tid] = 1.0f / (Psi[tid] + 1e-6f);
    mul[tid] = mu[m * DD + tid];
  }
  minv_l[tid] = Minv[(size_t)m * KK * KK + tid];
  __syncthreads();
  for (int idx = tid; idx < DD * KK; idx += 256)
    Wl[idx] = Lambda[(size_t)m * DD * KK + idx] * pinv[idx >> 4];
  __syncthreads();  // last block-wide barrier: shared params ready

  const int n = n0 + tid;
  const float cst = cconst[m];

  float u[KK];
#pragma unroll
  for (int k = 0; k < KK; ++k) u[k] = 0.0f;
  float q = 0.0f;
  const float4* X4 = reinterpret_cast<const float4*>(X + (size_t)n * DD);
#pragma unroll
  for (int d4 = 0; d4 < DD / 4; ++d4) {
    const float4 xv = X4[d4];
    const float xs[4] = {xv.x, xv.y, xv.z, xv.w};
#pragma unroll
    for (int s = 0; s < 4; ++s) {
      const int d = d4 * 4 + s;
      const float df = xs[s] - mul[d];
      q += df * df * pinv[d];
#pragma unroll
      for (int k = 0; k < KK; ++k) u[k] += Wl[d * KK + k] * df;
    }
  }

  float ez[KK];
  float udot = 0.0f;
#pragma unroll
  for (int i = 0; i < KK; ++i) {
    float s = 0.0f;
#pragma unroll
    for (int j = 0; j < KK; ++j) s += minv_l[i * KK + j] * u[j];
    ez[i] = s;
    udot += u[i] * s;
  }
  const float maha = q - udot;
  out[(size_t)n * MM + m] = cst - 0.5f * maha;  // logit; softmax later

#pragma unroll
  for (int k = 0; k < KK; ++k) ez_l[tid * KK + k] = ez[k];

  // ---- wave-local phase switch (no __syncthreads) ----
  __builtin_amdgcn_wave_barrier();
  asm volatile("s_waitcnt lgkmcnt(0)" ::: "memory");

  const int sbase = n0 + w * 64;  // first sample owned by this wave
  const float4* ezl4 =
      reinterpret_cast<const float4*>(ez_l + (size_t)w * 64 * KK);

  // e_z out: wave's 64 samples * 16 floats = 256 float4, coalesced
  float4* ezo = reinterpret_cast<float4*>(
      out + (size_t)NN * MM + ((size_t)m * NN + sbase) * KK);
#pragma unroll
  for (int it = 0; it < 4; ++it) ezo[it * 64 + l] = ezl4[it * 64 + l];

  // e_zz out: per iteration the wave writes one sample's full 16x16 tile
  // (64 lanes x float4 = 1KB, coalesced). lane l: row i_=l>>2, col-quad l&3.
  const int i_ = l >> 2, jq = l & 3;
  const float4 mreg = reinterpret_cast<const float4*>(minv_l)[l];
  float4* zzo = reinterpret_cast<float4*>(out + (size_t)NN * MM +
                                          (size_t)MM * NN * KK) +
                ((size_t)m * NN + sbase) * 64;
#pragma unroll 4
  for (int nl = 0; nl < 64; ++nl) {
    const float ezi = ez_l[((size_t)w * 64 + nl) * KK + i_];
    const float4 ezj = ezl4[nl * 4 + jq];
    float4 o;
    o.x = mreg.x + ezi * ezj.x;
    o.y = mreg.y + ezi * ezj.y;
    o.z = mreg.z + ezi * ezj.z;
    o.w = mreg.w + ezi * ezj.w;
    zzo[nl * 64 + l] = o;
  }
}

// ---------------------------------------------------------------------------
// Kernel 3: in-place softmax over the M=32 logits per sample.
// ---------------------------------------------------------------------------
__global__ __launch_bounds__(256) void mfa_softmax(float* __restrict__ out) {
  const int n = blockIdx.x * 256 + threadIdx.x;
  float4* p = reinterpret_cast<float4*>(out) + (size_t)n * (MM / 4);
  float v[MM];
#pragma unroll
  for (int i = 0; i < MM / 4; ++i) {
    const float4 t = p[i];
    v[4 * i] = t.x; v[4 * i + 1] = t.y; v[4 * i + 2] = t.z; v[4 * i + 3] = t.w;
  }
  float mx = -3.4e38f;
#pragma unroll
  for (int i = 0; i < MM; ++i) mx = fmaxf(mx, v[i]);
  float s = 0.0f;
#pragma unroll
  for (int i = 0; i < MM; ++i) { v[i] = expf(v[i] - mx); s += v[i]; }
  const float inv = 1.0f / s;
#pragma unroll
  for (int i = 0; i < MM / 4; ++i) {
    float4 t;
    t.x = v[4 * i] * inv; t.y = v[4 * i + 1] * inv;
    t.z = v[4 * i + 2] * inv; t.w = v[4 * i + 3] * inv;
    p[i] = t;
  }
}

extern "C" void kernel_launch(void* const* d_in, const int* in_sizes, int n_in,
                              void* d_out, int out_size, void* d_ws,
                              size_t ws_size, hipStream_t stream) {
  const float* X = (const float*)d_in[0];
  const float* pi = (const float*)d_in[1];
  const float* mu = (const float*)d_in[2];
  const float* Lambda = (const float*)d_in[3];
  const float* Psi = (const float*)d_in[4];
  float* out = (float*)d_out;

  float* Minv = (float*)d_ws;           // 32*256 floats = 32KB
  float* cconst = Minv + MM * KK * KK;  // 32 floats

  mfa_pre<<<MM, 256, 0, stream>>>(pi, Lambda, Psi, Minv, cconst);
  mfa_main<<<dim3(NN / 256, MM), 256, 0, stream>>>(X, mu, Lambda, Psi, Minv,
                                                   cconst, out);
  mfa_softmax<<<NN / 256, 256, 0, stream>>>(out);
}